// Round 1
// baseline (1350.318 us; speedup 1.0000x reference)
//
#include <hip/hip_runtime.h>
#include <hip/hip_bf16.h>

#define BTOK 8192
#define DDIM 1024
#define NEXP 8
#define KCAP 2048
#define HDIM 4096

typedef __attribute__((ext_vector_type(4))) float f32x4;
typedef __attribute__((ext_vector_type(8))) short bf16x8;

__device__ __forceinline__ unsigned short f2bf(float f) {
    union { float f; unsigned u; } v; v.f = f;
    unsigned r = v.u + 0x7fffu + ((v.u >> 16) & 1u);   // RNE
    return (unsigned short)(r >> 16);
}

// ---------------- router: gateT[e][b] = softmax(x@Wr + br) ----------------
__global__ __launch_bounds__(256) void router_kernel(
    const float* __restrict__ x, const float* __restrict__ Wr,
    const float* __restrict__ br, float* __restrict__ gateT) {
    __shared__ float wr_s[NEXP][DDIM];
    int t = threadIdx.x;
    for (int i = t; i < NEXP * DDIM; i += 256) {
        int e = i >> 10, d = i & 1023;
        wr_s[e][d] = Wr[d * NEXP + e];
    }
    __syncthreads();
    int wid = t >> 6, lane = t & 63;
    int b = blockIdx.x * 4 + wid;
    const float4* xr = (const float4*)(x + (size_t)b * DDIM);
    float4 xv[4];
#pragma unroll
    for (int j = 0; j < 4; j++) xv[j] = xr[j * 64 + lane];
    double acc[NEXP];
#pragma unroll
    for (int e = 0; e < NEXP; e++) {
        double a = 0.0;
#pragma unroll
        for (int j = 0; j < 4; j++) {
            float4 wv = ((const float4*)&wr_s[e][0])[j * 64 + lane];
            a += (double)xv[j].x * wv.x + (double)xv[j].y * wv.y
               + (double)xv[j].z * wv.z + (double)xv[j].w * wv.w;
        }
#pragma unroll
        for (int s = 1; s < 64; s <<= 1) a += __shfl_xor(a, s, 64);
        acc[e] = a + (double)br[e];
    }
    if (lane == 0) {
        double mx = acc[0];
#pragma unroll
        for (int e = 1; e < NEXP; e++) mx = fmax(mx, acc[e]);
        double p[NEXP]; double ssum = 0.0;
#pragma unroll
        for (int e = 0; e < NEXP; e++) { p[e] = exp(acc[e] - mx); ssum += p[e]; }
        double inv = 1.0 / ssum;
#pragma unroll
        for (int e = 0; e < NEXP; e++) gateT[e * BTOK + b] = (float)(p[e] * inv);
    }
}

// ---------------- radix select: K-th largest per expert ----------------
__global__ __launch_bounds__(256) void select_kernel(
    const float* __restrict__ gateT, unsigned* __restrict__ meta) {
    int e = blockIdx.x, t = threadIdx.x;
    const float* g = gateT + e * BTOK;
    __shared__ unsigned hist[256];
    __shared__ unsigned sh_prefix;
    __shared__ int sh_rem;
    if (t == 0) { sh_prefix = 0; sh_rem = KCAP; }
    __syncthreads();
    for (int pass = 0; pass < 4; pass++) {
        int shift = 24 - pass * 8;
        hist[t] = 0;
        __syncthreads();
        unsigned pfx = sh_prefix;
        for (int i = t; i < BTOK; i += 256) {
            unsigned key = __float_as_uint(g[i]);
            if (pass == 0 || (key >> (shift + 8)) == pfx)
                atomicAdd(&hist[(key >> shift) & 255u], 1u);
        }
        __syncthreads();
        if (t == 0) {
            int rem = sh_rem, cum = 0, d = 0;
            for (int dd = 255; dd >= 0; dd--) {
                cum += (int)hist[dd];
                if (cum >= rem) { d = dd; break; }
            }
            sh_rem = rem - (cum - (int)hist[d]);
            sh_prefix = (pfx << 8) | (unsigned)d;
        }
        __syncthreads();
    }
    unsigned cutoff = sh_prefix;
    int cnt = 0;
    for (int i = t; i < BTOK; i += 256)
        if (__float_as_uint(g[i]) > cutoff) cnt++;
    __shared__ int red[256];
    red[t] = cnt; __syncthreads();
    for (int s = 128; s > 0; s >>= 1) { if (t < s) red[t] += red[t + s]; __syncthreads(); }
    if (t == 0) { meta[e] = cutoff; meta[NEXP + e] = (unsigned)red[0]; }
}

// ---------------- build compact per-expert token lists ----------------
__global__ __launch_bounds__(256) void build_kernel(
    const float* __restrict__ gateT, const unsigned* __restrict__ meta,
    unsigned* __restrict__ cnt, int* __restrict__ idx_list, float* __restrict__ wt_list) {
    int e = blockIdx.y;
    int b = blockIdx.x * 256 + threadIdx.x;
    float gv = gateT[e * BTOK + b];
    unsigned key = __float_as_uint(gv);
    unsigned cutoff = meta[e];
    int ngt = (int)meta[NEXP + e];
    bool sel = key > cutoff;
    if (!sel && key == cutoff) {   // tie: lowest index first (jax.lax.top_k)
        const float* g = gateT + e * BTOK;
        int rank = 0;
        for (int j = 0; j < b; j++)
            if (__float_as_uint(g[j]) == cutoff) rank++;
        sel = (ngt + rank) < KCAP;
    }
    if (sel) {
        unsigned pos = atomicAdd(&cnt[e], 1u);
        if (pos < KCAP) {
            idx_list[e * KCAP + pos] = b;
            wt_list[e * KCAP + pos] = gv;
        }
    }
}

// ---------------- gemm1: h = relu(x[toks] @ W1 + b1), bf16 out ----------------
#define LDK1 72
__global__ __launch_bounds__(256) void gemm1_kernel(
    const float* __restrict__ x, const float* __restrict__ W1,
    const float* __restrict__ b1, const int* __restrict__ idx_list,
    unsigned short* __restrict__ h) {
    __shared__ unsigned short As[128][LDK1];
    __shared__ unsigned short Bs[128][LDK1];
    __shared__ int toks[128];
    int t = threadIdx.x;
    int m0 = blockIdx.x * 128, n0 = blockIdx.y * 128;
    if (t < 128) toks[t] = idx_list[m0 + t];
    __syncthreads();
    f32x4 acc[4][4] = {};
    int w = t >> 6, lane = t & 63;
    int wr = (w >> 1) * 64, wc = (w & 1) * 64;
    int fr = lane & 15, kg = lane >> 4;
    int bn = t & 127, bkh = (t >> 7) * 32;
    for (int kt = 0; kt < DDIM; kt += 64) {
        __syncthreads();
        // stage A: 128 rows x 64 k, fp32 gather -> bf16
#pragma unroll
        for (int i = 0; i < 8; i++) {
            int u = i * 256 + t;
            int row = u >> 4, kq = u & 15;
            float4 v = *(const float4*)(x + (size_t)toks[row] * DDIM + kt + kq * 4);
            short4 s;
            s.x = (short)f2bf(v.x); s.y = (short)f2bf(v.y);
            s.z = (short)f2bf(v.z); s.w = (short)f2bf(v.w);
            *(short4*)(&As[row][kq * 4]) = s;
        }
        // stage B: 64 k-rows x 128 n (k-strided coalesced scalar loads, b128 LDS writes)
        {
            const float* wp = W1 + (size_t)(kt + bkh) * HDIM + n0 + bn;
            union { unsigned short us[16]; int4 q[2]; } tb;
#pragma unroll
            for (int j = 0; j < 16; j++) tb.us[j] = f2bf(wp[(size_t)j * HDIM]);
            *(int4*)(&Bs[bn][bkh]) = tb.q[0];
            *(int4*)(&Bs[bn][bkh + 8]) = tb.q[1];
            const float* wp2 = wp + (size_t)16 * HDIM;
#pragma unroll
            for (int j = 0; j < 16; j++) tb.us[j] = f2bf(wp2[(size_t)j * HDIM]);
            *(int4*)(&Bs[bn][bkh + 16]) = tb.q[0];
            *(int4*)(&Bs[bn][bkh + 24]) = tb.q[1];
        }
        __syncthreads();
#pragma unroll
        for (int kk = 0; kk < 2; kk++) {
            bf16x8 af[4], bfr[4];
#pragma unroll
            for (int mf = 0; mf < 4; mf++)
                af[mf] = *(const bf16x8*)(&As[wr + mf * 16 + fr][kk * 32 + kg * 8]);
#pragma unroll
            for (int nf = 0; nf < 4; nf++)
                bfr[nf] = *(const bf16x8*)(&Bs[wc + nf * 16 + fr][kk * 32 + kg * 8]);
#pragma unroll
            for (int mf = 0; mf < 4; mf++)
#pragma unroll
                for (int nf = 0; nf < 4; nf++)
                    acc[mf][nf] = __builtin_amdgcn_mfma_f32_16x16x32_bf16(
                        af[mf], bfr[nf], acc[mf][nf], 0, 0, 0);
        }
    }
    int hi = lane >> 4;
#pragma unroll
    for (int nf = 0; nf < 4; nf++) {
        int col = n0 + wc + nf * 16 + (lane & 15);
        float bias = b1[col];
#pragma unroll
        for (int mf = 0; mf < 4; mf++) {
            int r0 = wr + mf * 16 + hi * 4;
#pragma unroll
            for (int r = 0; r < 4; r++) {
                float v = fmaxf(acc[mf][nf][r] + bias, 0.f);
                h[(size_t)(m0 + r0 + r) * HDIM + col] = f2bf(v);
            }
        }
    }
}

// ---------------- gemm2: out[toks] += w * (h @ W2 + b2) ----------------
#define LDK2 72
__global__ __launch_bounds__(256) void gemm2_kernel(
    const unsigned short* __restrict__ h, const float* __restrict__ W2,
    const float* __restrict__ b2, const int* __restrict__ idx_list,
    const float* __restrict__ wt_list, float* __restrict__ out) {
    __shared__ unsigned short As[64][LDK2];
    __shared__ unsigned short Bs[64][LDK2];
    __shared__ int toks[64];
    __shared__ float wts[64];
    int t = threadIdx.x;
    int m0 = blockIdx.x * 64, n0 = blockIdx.y * 64;
    if (t < 64) { toks[t] = idx_list[m0 + t]; wts[t] = wt_list[m0 + t]; }
    __syncthreads();
    f32x4 acc[2][2] = {};
    int w = t >> 6, lane = t & 63;
    int wr = (w >> 1) * 32, wc = (w & 1) * 32;
    int fr = lane & 15, kg = lane >> 4;
    int bn = t & 63, bkh = (t >> 6) * 16;
    for (int kt = 0; kt < HDIM; kt += 64) {
        __syncthreads();
        // stage A: 64 rows x 64 halves (bf16 direct)
#pragma unroll
        for (int i = 0; i < 2; i++) {
            int u = i * 256 + t;
            int row = u >> 3, kq = u & 7;
            *(int4*)(&As[row][kq * 8]) =
                *(const int4*)(h + (size_t)(m0 + row) * HDIM + kt + kq * 8);
        }
        // stage B: 64 k x 64 n fp32
        {
            const float* wp = W2 + (size_t)(kt + bkh) * DDIM + n0 + bn;
            union { unsigned short us[16]; int4 q[2]; } tb;
#pragma unroll
            for (int j = 0; j < 16; j++) tb.us[j] = f2bf(wp[(size_t)j * DDIM]);
            *(int4*)(&Bs[bn][bkh]) = tb.q[0];
            *(int4*)(&Bs[bn][bkh + 8]) = tb.q[1];
        }
        __syncthreads();
#pragma unroll
        for (int kk = 0; kk < 2; kk++) {
            bf16x8 af[2], bfr[2];
#pragma unroll
            for (int mf = 0; mf < 2; mf++)
                af[mf] = *(const bf16x8*)(&As[wr + mf * 16 + fr][kk * 32 + kg * 8]);
#pragma unroll
            for (int nf = 0; nf < 2; nf++)
                bfr[nf] = *(const bf16x8*)(&Bs[wc + nf * 16 + fr][kk * 32 + kg * 8]);
#pragma unroll
            for (int mf = 0; mf < 2; mf++)
#pragma unroll
                for (int nf = 0; nf < 2; nf++)
                    acc[mf][nf] = __builtin_amdgcn_mfma_f32_16x16x32_bf16(
                        af[mf], bfr[nf], acc[mf][nf], 0, 0, 0);
        }
    }
    int hi = lane >> 4;
#pragma unroll
    for (int nf = 0; nf < 2; nf++) {
        int col = n0 + wc + nf * 16 + (lane & 15);
        float bias = b2[col];
#pragma unroll
        for (int mf = 0; mf < 2; mf++) {
            int lr0 = wr + mf * 16 + hi * 4;
#pragma unroll
            for (int r = 0; r < 4; r++) {
                int lrow = lr0 + r;
                float wgt = wts[lrow];
                // unique (token,col) per expert; experts serialized => plain RMW
                out[(size_t)toks[lrow] * DDIM + col] += wgt * (acc[mf][nf][r] + bias);
            }
        }
    }
}

extern "C" void kernel_launch(void* const* d_in, const int* in_sizes, int n_in,
                              void* d_out, int out_size, void* d_ws, size_t ws_size,
                              hipStream_t stream) {
    const float* x  = (const float*)d_in[0];
    const float* Wr = (const float*)d_in[1];
    const float* br = (const float*)d_in[2];
    const float* W1 = (const float*)d_in[3];
    const float* b1 = (const float*)d_in[4];
    const float* W2 = (const float*)d_in[5];
    const float* b2 = (const float*)d_in[6];
    float* out = (float*)d_out;

    char* ws = (char*)d_ws;
    float*    gateT    = (float*)ws;                         // 256 KB
    unsigned* meta     = (unsigned*)(ws + 262144);           // cutoff[8], ngt[8]
    unsigned* cnt      = meta + 16;                          // 8
    int*      idx_list = (int*)(ws + 262400);                // 64 KB
    float*    wt_list  = (float*)(ws + 327936);              // 64 KB
    unsigned short* h  = (unsigned short*)(ws + 393472);     // 16 MB (per-expert reuse)

    size_t needed = 393472 + (size_t)KCAP * HDIM * 2;
    if (ws_size < needed) return;  // would fail validation cleanly

    hipMemsetAsync(d_out, 0, (size_t)out_size * sizeof(float), stream);
    hipMemsetAsync(cnt, 0, NEXP * sizeof(unsigned), stream);
    hipMemsetAsync(idx_list, 0, (size_t)NEXP * KCAP * (sizeof(int) + sizeof(float)), stream);

    router_kernel<<<dim3(BTOK / 4), 256, 0, stream>>>(x, Wr, br, gateT);
    select_kernel<<<dim3(NEXP), 256, 0, stream>>>(gateT, meta);
    build_kernel<<<dim3(BTOK / 256, NEXP), 256, 0, stream>>>(gateT, meta, cnt, idx_list, wt_list);

    for (int e = 0; e < NEXP; e++) {
        gemm1_kernel<<<dim3(KCAP / 128, HDIM / 128), 256, 0, stream>>>(
            x, W1 + (size_t)e * DDIM * HDIM, b1 + (size_t)e * HDIM,
            idx_list + (size_t)e * KCAP, h);
        gemm2_kernel<<<dim3(KCAP / 64, DDIM / 64), 256, 0, stream>>>(
            h, W2 + (size_t)e * HDIM * DDIM, b2 + (size_t)e * DDIM,
            idx_list + (size_t)e * KCAP, wt_list + (size_t)e * KCAP, out);
    }
}

// Round 2
// 775.288 us; speedup vs baseline: 1.7417x; 1.7417x over previous
//
#include <hip/hip_runtime.h>
#include <hip/hip_bf16.h>

#define BTOK 8192
#define DDIM 1024
#define NEXP 8
#define KCAP 2048
#define HDIM 4096

typedef __attribute__((ext_vector_type(4))) float f32x4;
typedef __attribute__((ext_vector_type(8))) short bf16x8;

__device__ __forceinline__ unsigned short f2bf(float f) {
    union { float f; unsigned u; } v; v.f = f;
    unsigned r = v.u + 0x7fffu + ((v.u >> 16) & 1u);   // RNE
    return (unsigned short)(r >> 16);
}

typedef __attribute__((address_space(3))) unsigned int lds_u32;
typedef __attribute__((address_space(1))) const unsigned int glb_u32;
__device__ __forceinline__ void gl_lds16(const void* g, void* l) {
    __builtin_amdgcn_global_load_lds((glb_u32*)g, (lds_u32*)l, 16, 0, 0);
}

// ---------------- router: gateT[e][b] = softmax(x@Wr + br); also x->bf16 ----------------
__global__ __launch_bounds__(256) void router_kernel(
    const float* __restrict__ x, const float* __restrict__ Wr,
    const float* __restrict__ br, float* __restrict__ gateT,
    unsigned short* __restrict__ xb) {
    __shared__ float wr_s[NEXP][DDIM];
    int t = threadIdx.x;
    for (int i = t; i < NEXP * DDIM; i += 256) {
        int e = i >> 10, d = i & 1023;
        wr_s[e][d] = Wr[d * NEXP + e];
    }
    __syncthreads();
    int wid = t >> 6, lane = t & 63;
    int b = blockIdx.x * 4 + wid;
    const float4* xr = (const float4*)(x + (size_t)b * DDIM);
    float4 xv[4];
#pragma unroll
    for (int j = 0; j < 4; j++) xv[j] = xr[j * 64 + lane];
    if (xb) {   // fused x -> bf16 (we already hold the row in registers)
#pragma unroll
        for (int j = 0; j < 4; j++) {
            short4 s;
            s.x = (short)f2bf(xv[j].x); s.y = (short)f2bf(xv[j].y);
            s.z = (short)f2bf(xv[j].z); s.w = (short)f2bf(xv[j].w);
            *(short4*)(xb + (size_t)b * DDIM + (j * 64 + lane) * 4) = s;
        }
    }
    double acc[NEXP];
#pragma unroll
    for (int e = 0; e < NEXP; e++) {
        double a = 0.0;
#pragma unroll
        for (int j = 0; j < 4; j++) {
            float4 wv = ((const float4*)&wr_s[e][0])[j * 64 + lane];
            a += (double)xv[j].x * wv.x + (double)xv[j].y * wv.y
               + (double)xv[j].z * wv.z + (double)xv[j].w * wv.w;
        }
#pragma unroll
        for (int s = 1; s < 64; s <<= 1) a += __shfl_xor(a, s, 64);
        acc[e] = a + (double)br[e];
    }
    if (lane == 0) {
        double mx = acc[0];
#pragma unroll
        for (int e = 1; e < NEXP; e++) mx = fmax(mx, acc[e]);
        double p[NEXP]; double ssum = 0.0;
#pragma unroll
        for (int e = 0; e < NEXP; e++) { p[e] = exp(acc[e] - mx); ssum += p[e]; }
        double inv = 1.0 / ssum;
#pragma unroll
        for (int e = 0; e < NEXP; e++) gateT[e * BTOK + b] = (float)(p[e] * inv);
    }
}

// ---------------- radix select: K-th largest per expert ----------------
__global__ __launch_bounds__(256) void select_kernel(
    const float* __restrict__ gateT, unsigned* __restrict__ meta) {
    int e = blockIdx.x, t = threadIdx.x;
    const float* g = gateT + e * BTOK;
    __shared__ unsigned hist[256];
    __shared__ unsigned sh_prefix;
    __shared__ int sh_rem;
    if (t == 0) { sh_prefix = 0; sh_rem = KCAP; }
    __syncthreads();
    for (int pass = 0; pass < 4; pass++) {
        int shift = 24 - pass * 8;
        hist[t] = 0;
        __syncthreads();
        unsigned pfx = sh_prefix;
        for (int i = t; i < BTOK; i += 256) {
            unsigned key = __float_as_uint(g[i]);
            if (pass == 0 || (key >> (shift + 8)) == pfx)
                atomicAdd(&hist[(key >> shift) & 255u], 1u);
        }
        __syncthreads();
        if (t == 0) {
            int rem = sh_rem, cum = 0, d = 0;
            for (int dd = 255; dd >= 0; dd--) {
                cum += (int)hist[dd];
                if (cum >= rem) { d = dd; break; }
            }
            sh_rem = rem - (cum - (int)hist[d]);
            sh_prefix = (pfx << 8) | (unsigned)d;
        }
        __syncthreads();
    }
    unsigned cutoff = sh_prefix;
    int cnt = 0;
    for (int i = t; i < BTOK; i += 256)
        if (__float_as_uint(g[i]) > cutoff) cnt++;
    __shared__ int red[256];
    red[t] = cnt; __syncthreads();
    for (int s = 128; s > 0; s >>= 1) { if (t < s) red[t] += red[t + s]; __syncthreads(); }
    if (t == 0) { meta[e] = cutoff; meta[NEXP + e] = (unsigned)red[0]; }
}

// ---------------- build: strictly-above-cutoff tokens ----------------
__global__ __launch_bounds__(256) void build_kernel(
    const float* __restrict__ gateT, const unsigned* __restrict__ meta,
    unsigned* __restrict__ cnt, int* __restrict__ idx_list, float* __restrict__ wt_list) {
    int e = blockIdx.y;
    int b = blockIdx.x * 256 + threadIdx.x;
    float gv = gateT[(size_t)e * BTOK + b];
    if (__float_as_uint(gv) > meta[e]) {
        unsigned pos = atomicAdd(&cnt[e], 1u);
        if (pos < KCAP) {
            idx_list[(size_t)e * KCAP + pos] = b;
            wt_list[(size_t)e * KCAP + pos] = gv;
        }
    }
}

// ---------------- ties: cooperative prefix scan, lowest index first ----------------
__global__ __launch_bounds__(256) void tie_kernel(
    const float* __restrict__ gateT, const unsigned* __restrict__ meta,
    unsigned* __restrict__ cnt, int* __restrict__ idx_list, float* __restrict__ wt_list) {
    int e = blockIdx.x, t = threadIdx.x;
    unsigned cutoff = meta[e];
    int need = KCAP - (int)meta[NEXP + e];
    const float* g = gateT + (size_t)e * BTOK;
    __shared__ int pre[256];
    int base = t * 32;
    int c = 0;
    for (int j = 0; j < 32; j++) c += (__float_as_uint(g[base + j]) == cutoff) ? 1 : 0;
    pre[t] = c;
    __syncthreads();
    for (int s = 1; s < 256; s <<= 1) {
        int v = (t >= s) ? pre[t - s] : 0;
        __syncthreads();
        pre[t] += v;
        __syncthreads();
    }
    int rank = pre[t] - c;   // exclusive prefix of tie count
    for (int j = 0; j < 32; j++) {
        float gv = g[base + j];
        if (__float_as_uint(gv) == cutoff) {
            if (rank < need) {
                unsigned pos = atomicAdd(&cnt[e], 1u);
                if (pos < KCAP) {
                    idx_list[(size_t)e * KCAP + pos] = base + j;
                    wt_list[(size_t)e * KCAP + pos] = gv;
                }
            }
            rank++;
        }
    }
}

// ---------------- transpose+convert: src[R][C] f32 -> dst[C][R] bf16 ----------------
__global__ __launch_bounds__(256) void tcvt_kernel(
    const float* __restrict__ src, unsigned short* __restrict__ dst, int R, int C) {
    __shared__ unsigned short tile[64][72];
    int c0 = blockIdx.x * 64, r0 = blockIdx.y * 64;
    int t = threadIdx.x;
    int cq = t & 15, rr = t >> 4;
#pragma unroll
    for (int ri = 0; ri < 4; ri++) {
        int r = ri * 16 + rr;
        float4 v = *(const float4*)(src + (size_t)(r0 + r) * C + c0 + cq * 4);
        tile[cq * 4 + 0][r] = f2bf(v.x);
        tile[cq * 4 + 1][r] = f2bf(v.y);
        tile[cq * 4 + 2][r] = f2bf(v.z);
        tile[cq * 4 + 3][r] = f2bf(v.w);
    }
    __syncthreads();
    int rq = t & 15, cc = t >> 4;
#pragma unroll
    for (int ci = 0; ci < 4; ci++) {
        int c = ci * 16 + cc;
        *(short4*)(dst + (size_t)(c0 + c) * R + r0 + rq * 4) = *(const short4*)&tile[c][rq * 4];
    }
}

// ============ main-path GEMMs: bf16 operands, global_load_lds, XOR-swizzled LDS ============
// LDS layout: [128 rows][64 bf16] linear; swizzle byte ^= ((row&7)<<4), applied on the
// pre-swizzled GLOBAL source (global_load_lds writes linearly) and on ds_read (rule #21).

// gemm1: h[m][n] = relu(xb[toks[m]] @ W1T[n] + b1[n])
__global__ __launch_bounds__(256) void gemm1_kernel(
    const unsigned short* __restrict__ xb, const unsigned short* __restrict__ w1t,
    const float* __restrict__ b1, const int* __restrict__ idx_list,
    unsigned short* __restrict__ h) {
    __shared__ unsigned short As[128 * 64];
    __shared__ unsigned short Bs[128 * 64];
    __shared__ int toks[128];
    int t = threadIdx.x;
    int m0 = blockIdx.x * 128, n0 = blockIdx.y * 128;
    if (t < 128) toks[t] = idx_list[m0 + t];
    __syncthreads();
    int w = t >> 6, lane = t & 63;
    int lrow8 = lane >> 3, lcol = lane & 7;
    unsigned swz = (unsigned)(((lcol ^ lrow8) & 7) << 4);
    const char* aptr[4]; const char* bptr[4];
    unsigned short* alds[4]; unsigned short* blds[4];
#pragma unroll
    for (int i = 0; i < 4; i++) {
        int rr = i * 32 + w * 8 + lrow8;
        aptr[i] = (const char*)(xb + (size_t)toks[rr] * DDIM) + swz;
        bptr[i] = (const char*)(w1t + (size_t)(n0 + rr) * DDIM) + swz;
        alds[i] = As + (i * 32 + w * 8) * 64;   // wave-uniform
        blds[i] = Bs + (i * 32 + w * 8) * 64;
    }
    f32x4 acc[4][4] = {};
    int fr = lane & 15, kg = lane >> 4;
    int wr = (w >> 1) * 64, wc = (w & 1) * 64;
    for (int kt = 0; kt < DDIM; kt += 64) {
        __syncthreads();
#pragma unroll
        for (int i = 0; i < 4; i++) {
            gl_lds16(aptr[i], alds[i]);
            gl_lds16(bptr[i], blds[i]);
            aptr[i] += 128; bptr[i] += 128;
        }
        __syncthreads();
#pragma unroll
        for (int kk = 0; kk < 2; kk++) {
            bf16x8 af[4], bf[4];
#pragma unroll
            for (int mf = 0; mf < 4; mf++) {
                int r = wr + mf * 16 + fr;
                int byte = (r * 128 + kk * 64 + kg * 16) ^ ((r & 7) << 4);
                af[mf] = *(const bf16x8*)((const char*)As + byte);
            }
#pragma unroll
            for (int nf = 0; nf < 4; nf++) {
                int r = wc + nf * 16 + fr;
                int byte = (r * 128 + kk * 64 + kg * 16) ^ ((r & 7) << 4);
                bf[nf] = *(const bf16x8*)((const char*)Bs + byte);
            }
#pragma unroll
            for (int mf = 0; mf < 4; mf++)
#pragma unroll
                for (int nf = 0; nf < 4; nf++)
                    acc[mf][nf] = __builtin_amdgcn_mfma_f32_16x16x32_bf16(
                        af[mf], bf[nf], acc[mf][nf], 0, 0, 0);
        }
    }
    int hi = lane >> 4;
#pragma unroll
    for (int nf = 0; nf < 4; nf++) {
        int col = n0 + wc + nf * 16 + fr;
        float bias = b1[col];
#pragma unroll
        for (int mf = 0; mf < 4; mf++) {
            int r0 = wr + mf * 16 + hi * 4;
#pragma unroll
            for (int r = 0; r < 4; r++) {
                float v = fmaxf(acc[mf][nf][r] + bias, 0.f);
                h[(size_t)(m0 + r0 + r) * HDIM + col] = f2bf(v);
            }
        }
    }
}

// gemm2: out[toks[m]][n] += wt[m] * (h[m] @ W2T[n] + b2[n]); split-K over blockIdx.z
__global__ __launch_bounds__(256) void gemm2_kernel(
    const unsigned short* __restrict__ h, const unsigned short* __restrict__ w2t,
    const float* __restrict__ b2, const int* __restrict__ idx_list,
    const float* __restrict__ wt_list, float* __restrict__ out) {
    __shared__ unsigned short As[128 * 64];
    __shared__ unsigned short Bs[128 * 64];
    __shared__ int toks[128];
    __shared__ float wts[128];
    int t = threadIdx.x;
    int m0 = blockIdx.x * 128, n0 = blockIdx.y * 128;
    int z = blockIdx.z;                 // split-K half
    if (t < 128) { toks[t] = idx_list[m0 + t]; wts[t] = wt_list[m0 + t]; }
    __syncthreads();
    int w = t >> 6, lane = t & 63;
    int lrow8 = lane >> 3, lcol = lane & 7;
    unsigned swz = (unsigned)(((lcol ^ lrow8) & 7) << 4);
    const char* aptr[4]; const char* bptr[4];
    unsigned short* alds[4]; unsigned short* blds[4];
#pragma unroll
    for (int i = 0; i < 4; i++) {
        int rr = i * 32 + w * 8 + lrow8;
        aptr[i] = (const char*)(h + (size_t)(m0 + rr) * HDIM + z * 2048) + swz;
        bptr[i] = (const char*)(w2t + (size_t)(n0 + rr) * HDIM + z * 2048) + swz;
        alds[i] = As + (i * 32 + w * 8) * 64;
        blds[i] = Bs + (i * 32 + w * 8) * 64;
    }
    f32x4 acc[4][4] = {};
    int fr = lane & 15, kg = lane >> 4;
    int wr = (w >> 1) * 64, wc = (w & 1) * 64;
    for (int kt = 0; kt < 2048; kt += 64) {
        __syncthreads();
#pragma unroll
        for (int i = 0; i < 4; i++) {
            gl_lds16(aptr[i], alds[i]);
            gl_lds16(bptr[i], blds[i]);
            aptr[i] += 128; bptr[i] += 128;
        }
        __syncthreads();
#pragma unroll
        for (int kk = 0; kk < 2; kk++) {
            bf16x8 af[4], bf[4];
#pragma unroll
            for (int mf = 0; mf < 4; mf++) {
                int r = wr + mf * 16 + fr;
                int byte = (r * 128 + kk * 64 + kg * 16) ^ ((r & 7) << 4);
                af[mf] = *(const bf16x8*)((const char*)As + byte);
            }
#pragma unroll
            for (int nf = 0; nf < 4; nf++) {
                int r = wc + nf * 16 + fr;
                int byte = (r * 128 + kk * 64 + kg * 16) ^ ((r & 7) << 4);
                bf[nf] = *(const bf16x8*)((const char*)Bs + byte);
            }
#pragma unroll
            for (int mf = 0; mf < 4; mf++)
#pragma unroll
                for (int nf = 0; nf < 4; nf++)
                    acc[mf][nf] = __builtin_amdgcn_mfma_f32_16x16x32_bf16(
                        af[mf], bf[nf], acc[mf][nf], 0, 0, 0);
        }
    }
    int hi = lane >> 4;
#pragma unroll
    for (int nf = 0; nf < 4; nf++) {
        int col = n0 + wc + nf * 16 + fr;
        float bias = (z == 0) ? b2[col] : 0.f;
#pragma unroll
        for (int mf = 0; mf < 4; mf++) {
            int r0 = wr + mf * 16 + hi * 4;
#pragma unroll
            for (int r = 0; r < 4; r++) {
                int lrow = r0 + r;
                atomicAdd(&out[(size_t)toks[lrow] * DDIM + col],
                          wts[lrow] * (acc[mf][nf][r] + bias));
            }
        }
    }
}

// ============ fallback GEMMs (fp32 operands, small ws) — round-1 versions ============
#define LDK1 72
__global__ __launch_bounds__(256) void gemm1_fb(
    const float* __restrict__ x, const float* __restrict__ W1,
    const float* __restrict__ b1, const int* __restrict__ idx_list,
    unsigned short* __restrict__ h) {
    __shared__ unsigned short As[128][LDK1];
    __shared__ unsigned short Bs[128][LDK1];
    __shared__ int toks[128];
    int t = threadIdx.x;
    int m0 = blockIdx.x * 128, n0 = blockIdx.y * 128;
    if (t < 128) toks[t] = idx_list[m0 + t];
    __syncthreads();
    f32x4 acc[4][4] = {};
    int w = t >> 6, lane = t & 63;
    int wr = (w >> 1) * 64, wc = (w & 1) * 64;
    int fr = lane & 15, kg = lane >> 4;
    int bn = t & 127, bkh = (t >> 7) * 32;
    for (int kt = 0; kt < DDIM; kt += 64) {
        __syncthreads();
#pragma unroll
        for (int i = 0; i < 8; i++) {
            int u = i * 256 + t;
            int row = u >> 4, kq = u & 15;
            float4 v = *(const float4*)(x + (size_t)toks[row] * DDIM + kt + kq * 4);
            short4 s;
            s.x = (short)f2bf(v.x); s.y = (short)f2bf(v.y);
            s.z = (short)f2bf(v.z); s.w = (short)f2bf(v.w);
            *(short4*)(&As[row][kq * 4]) = s;
        }
        {
            const float* wp = W1 + (size_t)(kt + bkh) * HDIM + n0 + bn;
            union { unsigned short us[16]; int4 q[2]; } tb;
#pragma unroll
            for (int j = 0; j < 16; j++) tb.us[j] = f2bf(wp[(size_t)j * HDIM]);
            *(int4*)(&Bs[bn][bkh]) = tb.q[0];
            *(int4*)(&Bs[bn][bkh + 8]) = tb.q[1];
            const float* wp2 = wp + (size_t)16 * HDIM;
#pragma unroll
            for (int j = 0; j < 16; j++) tb.us[j] = f2bf(wp2[(size_t)j * HDIM]);
            *(int4*)(&Bs[bn][bkh + 16]) = tb.q[0];
            *(int4*)(&Bs[bn][bkh + 24]) = tb.q[1];
        }
        __syncthreads();
#pragma unroll
        for (int kk = 0; kk < 2; kk++) {
            bf16x8 af[4], bfr[4];
#pragma unroll
            for (int mf = 0; mf < 4; mf++)
                af[mf] = *(const bf16x8*)(&As[wr + mf * 16 + fr][kk * 32 + kg * 8]);
#pragma unroll
            for (int nf = 0; nf < 4; nf++)
                bfr[nf] = *(const bf16x8*)(&Bs[wc + nf * 16 + fr][kk * 32 + kg * 8]);
#pragma unroll
            for (int mf = 0; mf < 4; mf++)
#pragma unroll
                for (int nf = 0; nf < 4; nf++)
                    acc[mf][nf] = __builtin_amdgcn_mfma_f32_16x16x32_bf16(
                        af[mf], bfr[nf], acc[mf][nf], 0, 0, 0);
        }
    }
    int hi = lane >> 4;
#pragma unroll
    for (int nf = 0; nf < 4; nf++) {
        int col = n0 + wc + nf * 16 + (lane & 15);
        float bias = b1[col];
#pragma unroll
        for (int mf = 0; mf < 4; mf++) {
            int r0 = wr + mf * 16 + hi * 4;
#pragma unroll
            for (int r = 0; r < 4; r++) {
                float v = fmaxf(acc[mf][nf][r] + bias, 0.f);
                h[(size_t)(m0 + r0 + r) * HDIM + col] = f2bf(v);
            }
        }
    }
}

#define LDK2 72
__global__ __launch_bounds__(256) void gemm2_fb(
    const unsigned short* __restrict__ h, const float* __restrict__ W2,
    const float* __restrict__ b2, const int* __restrict__ idx_list,
    const float* __restrict__ wt_list, float* __restrict__ out) {
    __shared__ unsigned short As[64][LDK2];
    __shared__ unsigned short Bs[64][LDK2];
    __shared__ int toks[64];
    __shared__ float wts[64];
    int t = threadIdx.x;
    int m0 = blockIdx.x * 64, n0 = blockIdx.y * 64;
    if (t < 64) { toks[t] = idx_list[m0 + t]; wts[t] = wt_list[m0 + t]; }
    __syncthreads();
    f32x4 acc[2][2] = {};
    int w = t >> 6, lane = t & 63;
    int wr = (w >> 1) * 32, wc = (w & 1) * 32;
    int fr = lane & 15, kg = lane >> 4;
    int bn = t & 63, bkh = (t >> 6) * 16;
    for (int kt = 0; kt < HDIM; kt += 64) {
        __syncthreads();
#pragma unroll
        for (int i = 0; i < 2; i++) {
            int u = i * 256 + t;
            int row = u >> 3, kq = u & 7;
            *(int4*)(&As[row][kq * 8]) =
                *(const int4*)(h + (size_t)(m0 + row) * HDIM + kt + kq * 8);
        }
        {
            const float* wp = W2 + (size_t)(kt + bkh) * DDIM + n0 + bn;
            union { unsigned short us[16]; int4 q[2]; } tb;
#pragma unroll
            for (int j = 0; j < 16; j++) tb.us[j] = f2bf(wp[(size_t)j * DDIM]);
            *(int4*)(&Bs[bn][bkh]) = tb.q[0];
            *(int4*)(&Bs[bn][bkh + 8]) = tb.q[1];
        }
        __syncthreads();
#pragma unroll
        for (int kk = 0; kk < 2; kk++) {
            bf16x8 af[2], bfr[2];
#pragma unroll
            for (int mf = 0; mf < 2; mf++)
                af[mf] = *(const bf16x8*)(&As[wr + mf * 16 + fr][kk * 32 + kg * 8]);
#pragma unroll
            for (int nf = 0; nf < 2; nf++)
                bfr[nf] = *(const bf16x8*)(&Bs[wc + nf * 16 + fr][kk * 32 + kg * 8]);
#pragma unroll
            for (int mf = 0; mf < 2; mf++)
#pragma unroll
                for (int nf = 0; nf < 2; nf++)
                    acc[mf][nf] = __builtin_amdgcn_mfma_f32_16x16x32_bf16(
                        af[mf], bfr[nf], acc[mf][nf], 0, 0, 0);
        }
    }
    int hi = lane >> 4;
#pragma unroll
    for (int nf = 0; nf < 2; nf++) {
        int col = n0 + wc + nf * 16 + (lane & 15);
        float bias = b2[col];
#pragma unroll
        for (int mf = 0; mf < 2; mf++) {
            int lr0 = wr + mf * 16 + hi * 4;
#pragma unroll
            for (int r = 0; r < 4; r++) {
                int lrow = lr0 + r;
                out[(size_t)toks[lrow] * DDIM + col] += wts[lrow] * (acc[mf][nf][r] + bias);
            }
        }
    }
}

extern "C" void kernel_launch(void* const* d_in, const int* in_sizes, int n_in,
                              void* d_out, int out_size, void* d_ws, size_t ws_size,
                              hipStream_t stream) {
    const float* x  = (const float*)d_in[0];
    const float* Wr = (const float*)d_in[1];
    const float* br = (const float*)d_in[2];
    const float* W1 = (const float*)d_in[3];
    const float* b1 = (const float*)d_in[4];
    const float* W2 = (const float*)d_in[5];
    const float* b2 = (const float*)d_in[6];
    float* out = (float*)d_out;

    char* ws = (char*)d_ws;
    float*    gateT    = (float*)ws;                         // 256 KB
    unsigned* meta     = (unsigned*)(ws + 262144);           // cutoff[8], ngt[8]
    unsigned* cnt      = meta + 16;                          // 8
    int*      idx_list = (int*)(ws + 262400);                // 64 KB
    float*    wt_list  = (float*)(ws + 327936);              // 64 KB
    // main plan buffers
    unsigned short* xbuf = (unsigned short*)(ws + 393472);              // 16 MB
    unsigned short* w1t  = (unsigned short*)(ws + 17170688);            // 8 MB
    unsigned short* w2t  = (unsigned short*)(ws + 25559296);            // 8 MB
    unsigned short* hbuf = (unsigned short*)(ws + 33947904);            // 16 MB
    const size_t NEED_MAIN = 50725120;
    // fallback plan
    unsigned short* hfb  = (unsigned short*)(ws + 393472);
    const size_t NEED_FB = 393472 + (size_t)KCAP * HDIM * 2;

    bool main_plan = (ws_size >= NEED_MAIN);
    if (!main_plan && ws_size < NEED_FB) return;

    hipMemsetAsync(d_out, 0, (size_t)out_size * sizeof(float), stream);
    hipMemsetAsync(cnt, 0, NEXP * sizeof(unsigned), stream);

    router_kernel<<<dim3(BTOK / 4), 256, 0, stream>>>(x, Wr, br, gateT,
                                                      main_plan ? xbuf : (unsigned short*)nullptr);
    select_kernel<<<dim3(NEXP), 256, 0, stream>>>(gateT, meta);
    build_kernel<<<dim3(BTOK / 256, NEXP), 256, 0, stream>>>(gateT, meta, cnt, idx_list, wt_list);
    tie_kernel<<<dim3(NEXP), 256, 0, stream>>>(gateT, meta, cnt, idx_list, wt_list);

    if (main_plan) {
        for (int e = 0; e < NEXP; e++) {
            // W1[e]: [1024][4096] -> w1t [4096][1024] bf16
            tcvt_kernel<<<dim3(HDIM / 64, DDIM / 64), 256, 0, stream>>>(
                W1 + (size_t)e * DDIM * HDIM, w1t, DDIM, HDIM);
            gemm1_kernel<<<dim3(KCAP / 128, HDIM / 128), 256, 0, stream>>>(
                xbuf, w1t, b1 + (size_t)e * HDIM, idx_list + (size_t)e * KCAP, hbuf);
            // W2[e]: [4096][1024] -> w2t [1024][4096] bf16
            tcvt_kernel<<<dim3(DDIM / 64, HDIM / 64), 256, 0, stream>>>(
                W2 + (size_t)e * HDIM * DDIM, w2t, HDIM, DDIM);
            gemm2_kernel<<<dim3(KCAP / 128, DDIM / 128, 2), 256, 0, stream>>>(
                hbuf, w2t, b2 + (size_t)e * DDIM, idx_list + (size_t)e * KCAP,
                wt_list + (size_t)e * KCAP, out);
        }
    } else {
        for (int e = 0; e < NEXP; e++) {
            gemm1_fb<<<dim3(KCAP / 128, HDIM / 128), 256, 0, stream>>>(
                x, W1 + (size_t)e * DDIM * HDIM, b1 + (size_t)e * HDIM,
                idx_list + (size_t)e * KCAP, hfb);
            gemm2_fb<<<dim3(KCAP / 64, DDIM / 64), 256, 0, stream>>>(
                hfb, W2 + (size_t)e * HDIM * DDIM, b2 + (size_t)e * DDIM,
                idx_list + (size_t)e * KCAP, wt_list + (size_t)e * KCAP, out);
        }
    }
}

// Round 3
// 626.839 us; speedup vs baseline: 2.1542x; 1.2368x over previous
//
#include <hip/hip_runtime.h>
#include <hip/hip_bf16.h>

#define BTOK 8192
#define DDIM 1024
#define NEXP 8
#define KCAP 2048
#define HDIM 4096
#define MB ((size_t)1048576)

typedef __attribute__((ext_vector_type(4))) float f32x4;
typedef __attribute__((ext_vector_type(8))) short bf16x8;

__device__ __forceinline__ unsigned short f2bf(float f) {
    union { float f; unsigned u; } v; v.f = f;
    unsigned r = v.u + 0x7fffu + ((v.u >> 16) & 1u);   // RNE
    return (unsigned short)(r >> 16);
}

typedef __attribute__((address_space(3))) unsigned int lds_u32;
typedef __attribute__((address_space(1))) const unsigned int glb_u32;
__device__ __forceinline__ void gl_lds16(const void* g, void* l) {
    __builtin_amdgcn_global_load_lds((glb_u32*)g, (lds_u32*)l, 16, 0, 0);
}

// ---------------- router: gateT[e][b] = softmax(x@Wr + br); also x->bf16 ----------------
__global__ __launch_bounds__(256) void router_kernel(
    const float* __restrict__ x, const float* __restrict__ Wr,
    const float* __restrict__ br, float* __restrict__ gateT,
    unsigned short* __restrict__ xb) {
    __shared__ float wr_s[NEXP][DDIM];
    int t = threadIdx.x;
    for (int i = t; i < NEXP * DDIM; i += 256) {
        int e = i >> 10, d = i & 1023;
        wr_s[e][d] = Wr[d * NEXP + e];
    }
    __syncthreads();
    int wid = t >> 6, lane = t & 63;
    int b = blockIdx.x * 4 + wid;
    const float4* xr = (const float4*)(x + (size_t)b * DDIM);
    float4 xv[4];
#pragma unroll
    for (int j = 0; j < 4; j++) xv[j] = xr[j * 64 + lane];
#pragma unroll
    for (int j = 0; j < 4; j++) {
        short4 s;
        s.x = (short)f2bf(xv[j].x); s.y = (short)f2bf(xv[j].y);
        s.z = (short)f2bf(xv[j].z); s.w = (short)f2bf(xv[j].w);
        *(short4*)(xb + (size_t)b * DDIM + (j * 64 + lane) * 4) = s;
    }
    double acc[NEXP];
#pragma unroll
    for (int e = 0; e < NEXP; e++) {
        double a = 0.0;
#pragma unroll
        for (int j = 0; j < 4; j++) {
            float4 wv = ((const float4*)&wr_s[e][0])[j * 64 + lane];
            a += (double)xv[j].x * wv.x + (double)xv[j].y * wv.y
               + (double)xv[j].z * wv.z + (double)xv[j].w * wv.w;
        }
#pragma unroll
        for (int s = 1; s < 64; s <<= 1) a += __shfl_xor(a, s, 64);
        acc[e] = a + (double)br[e];
    }
    if (lane == 0) {
        double mx = acc[0];
#pragma unroll
        for (int e = 1; e < NEXP; e++) mx = fmax(mx, acc[e]);
        double p[NEXP]; double ssum = 0.0;
#pragma unroll
        for (int e = 0; e < NEXP; e++) { p[e] = exp(acc[e] - mx); ssum += p[e]; }
        double inv = 1.0 / ssum;
#pragma unroll
        for (int e = 0; e < NEXP; e++) gateT[e * BTOK + b] = (float)(p[e] * inv);
    }
}

// ---------------- radix select: K-th largest per expert ----------------
__global__ __launch_bounds__(256) void select_kernel(
    const float* __restrict__ gateT, unsigned* __restrict__ meta) {
    int e = blockIdx.x, t = threadIdx.x;
    const float* g = gateT + e * BTOK;
    __shared__ unsigned hist[256];
    __shared__ unsigned sh_prefix;
    __shared__ int sh_rem;
    if (t == 0) { sh_prefix = 0; sh_rem = KCAP; }
    __syncthreads();
    for (int pass = 0; pass < 4; pass++) {
        int shift = 24 - pass * 8;
        hist[t] = 0;
        __syncthreads();
        unsigned pfx = sh_prefix;
        for (int i = t; i < BTOK; i += 256) {
            unsigned key = __float_as_uint(g[i]);
            if (pass == 0 || (key >> (shift + 8)) == pfx)
                atomicAdd(&hist[(key >> shift) & 255u], 1u);
        }
        __syncthreads();
        if (t == 0) {
            int rem = sh_rem, cum = 0, d = 0;
            for (int dd = 255; dd >= 0; dd--) {
                cum += (int)hist[dd];
                if (cum >= rem) { d = dd; break; }
            }
            sh_rem = rem - (cum - (int)hist[d]);
            sh_prefix = (pfx << 8) | (unsigned)d;
        }
        __syncthreads();
    }
    unsigned cutoff = sh_prefix;
    int cnt = 0;
    for (int i = t; i < BTOK; i += 256)
        if (__float_as_uint(g[i]) > cutoff) cnt++;
    __shared__ int red[256];
    red[t] = cnt; __syncthreads();
    for (int s = 128; s > 0; s >>= 1) { if (t < s) red[t] += red[t + s]; __syncthreads(); }
    if (t == 0) { meta[e] = cutoff; meta[NEXP + e] = (unsigned)red[0]; }
}

// ---------------- build: strictly-above-cutoff tokens ----------------
__global__ __launch_bounds__(256) void build_kernel(
    const float* __restrict__ gateT, const unsigned* __restrict__ meta,
    unsigned* __restrict__ cnt, int* __restrict__ idx_list, float* __restrict__ wt_list) {
    int e = blockIdx.y;
    int b = blockIdx.x * 256 + threadIdx.x;
    float gv = gateT[(size_t)e * BTOK + b];
    if (__float_as_uint(gv) > meta[e]) {
        unsigned pos = atomicAdd(&cnt[e], 1u);
        if (pos < KCAP) {
            idx_list[(size_t)e * KCAP + pos] = b;
            wt_list[(size_t)e * KCAP + pos] = gv;
        }
    }
}

// ---------------- ties: cooperative prefix scan, lowest index first ----------------
__global__ __launch_bounds__(256) void tie_kernel(
    const float* __restrict__ gateT, const unsigned* __restrict__ meta,
    unsigned* __restrict__ cnt, int* __restrict__ idx_list, float* __restrict__ wt_list) {
    int e = blockIdx.x, t = threadIdx.x;
    unsigned cutoff = meta[e];
    int need = KCAP - (int)meta[NEXP + e];
    const float* g = gateT + (size_t)e * BTOK;
    __shared__ int pre[256];
    int base = t * 32;
    int c = 0;
    for (int j = 0; j < 32; j++) c += (__float_as_uint(g[base + j]) == cutoff) ? 1 : 0;
    pre[t] = c;
    __syncthreads();
    for (int s = 1; s < 256; s <<= 1) {
        int v = (t >= s) ? pre[t - s] : 0;
        __syncthreads();
        pre[t] += v;
        __syncthreads();
    }
    int rank = pre[t] - c;   // exclusive prefix of tie count
    for (int j = 0; j < 32; j++) {
        float gv = g[base + j];
        if (__float_as_uint(gv) == cutoff) {
            if (rank < need) {
                unsigned pos = atomicAdd(&cnt[e], 1u);
                if (pos < KCAP) {
                    idx_list[(size_t)e * KCAP + pos] = base + j;
                    wt_list[(size_t)e * KCAP + pos] = gv;
                }
            }
            rank++;
        }
    }
}

// ---------------- inverse map: inv[e][token] = slot ----------------
__global__ __launch_bounds__(256) void invb_kernel(
    const int* __restrict__ idx_list, int* __restrict__ inv) {
    int i = blockIdx.x * 256 + threadIdx.x;        // 0 .. NEXP*KCAP-1
    int e = i >> 11, slot = i & (KCAP - 1);
    inv[(size_t)e * BTOK + idx_list[i]] = slot;
}

// ---------------- transpose+convert: src[R][C] f32 -> dst[C][R] bf16 (per z) ----------------
__global__ __launch_bounds__(256) void tcvt_kernel(
    const float* __restrict__ src, unsigned short* __restrict__ dst, int R, int C) {
    size_t zoff = (size_t)blockIdx.z * R * C;
    src += zoff; dst += zoff;
    __shared__ unsigned short tile[64][72];
    int c0 = blockIdx.x * 64, r0 = blockIdx.y * 64;
    int t = threadIdx.x;
    int cq = t & 15, rr = t >> 4;
#pragma unroll
    for (int ri = 0; ri < 4; ri++) {
        int r = ri * 16 + rr;
        float4 v = *(const float4*)(src + (size_t)(r0 + r) * C + c0 + cq * 4);
        tile[cq * 4 + 0][r] = f2bf(v.x);
        tile[cq * 4 + 1][r] = f2bf(v.y);
        tile[cq * 4 + 2][r] = f2bf(v.z);
        tile[cq * 4 + 3][r] = f2bf(v.w);
    }
    __syncthreads();
    int rq = t & 15, cc = t >> 4;
#pragma unroll
    for (int ci = 0; ci < 4; ci++) {
        int c = ci * 16 + cc;
        *(short4*)(dst + (size_t)(c0 + c) * R + r0 + rq * 4) = *(const short4*)&tile[c][rq * 4];
    }
}

// ============ GEMMs: bf16 operands, global_load_lds w16, XOR-swizzled LDS ============
// Swizzle byte ^= ((row&7)<<4) applied on pre-swizzled GLOBAL source (gl_lds writes
// linearly, rule #21) and on ds_read.

// gemm1: h[e][m][n] = relu(xb[toks[e][m]] @ W1T[e][n] + b1[e][n]);  z = expert
__global__ __launch_bounds__(256) void gemm1_kernel(
    const unsigned short* __restrict__ xb, const unsigned short* __restrict__ w1t,
    const float* __restrict__ b1, const int* __restrict__ idx_list,
    unsigned short* __restrict__ h) {
    int e = blockIdx.z;
    w1t     += (size_t)e * DDIM * HDIM;
    b1      += (size_t)e * HDIM;
    idx_list += (size_t)e * KCAP;
    h       += (size_t)e * KCAP * HDIM;
    __shared__ unsigned short As[128 * 64];
    __shared__ unsigned short Bs[128 * 64];
    __shared__ int toks[128];
    int t = threadIdx.x;
    int m0 = blockIdx.x * 128, n0 = blockIdx.y * 128;
    if (t < 128) toks[t] = idx_list[m0 + t];
    __syncthreads();
    int w = t >> 6, lane = t & 63;
    int lrow8 = lane >> 3, lcol = lane & 7;
    unsigned swz = (unsigned)(((lcol ^ lrow8) & 7) << 4);
    const char* aptr[4]; const char* bptr[4];
    unsigned short* alds[4]; unsigned short* blds[4];
#pragma unroll
    for (int i = 0; i < 4; i++) {
        int rr = i * 32 + w * 8 + lrow8;
        aptr[i] = (const char*)(xb + (size_t)toks[rr] * DDIM) + swz;
        bptr[i] = (const char*)(w1t + (size_t)(n0 + rr) * DDIM) + swz;
        alds[i] = As + (i * 32 + w * 8) * 64;   // wave-uniform
        blds[i] = Bs + (i * 32 + w * 8) * 64;
    }
    f32x4 acc[4][4] = {};
    int fr = lane & 15, kg = lane >> 4;
    int wr = (w >> 1) * 64, wc = (w & 1) * 64;
    for (int kt = 0; kt < DDIM; kt += 64) {
        __syncthreads();
#pragma unroll
        for (int i = 0; i < 4; i++) {
            gl_lds16(aptr[i], alds[i]);
            gl_lds16(bptr[i], blds[i]);
            aptr[i] += 128; bptr[i] += 128;
        }
        __syncthreads();
#pragma unroll
        for (int kk = 0; kk < 2; kk++) {
            bf16x8 af[4], bf[4];
#pragma unroll
            for (int mf = 0; mf < 4; mf++) {
                int r = wr + mf * 16 + fr;
                int byte = (r * 128 + kk * 64 + kg * 16) ^ ((r & 7) << 4);
                af[mf] = *(const bf16x8*)((const char*)As + byte);
            }
#pragma unroll
            for (int nf = 0; nf < 4; nf++) {
                int r = wc + nf * 16 + fr;
                int byte = (r * 128 + kk * 64 + kg * 16) ^ ((r & 7) << 4);
                bf[nf] = *(const bf16x8*)((const char*)Bs + byte);
            }
#pragma unroll
            for (int mf = 0; mf < 4; mf++)
#pragma unroll
                for (int nf = 0; nf < 4; nf++)
                    acc[mf][nf] = __builtin_amdgcn_mfma_f32_16x16x32_bf16(
                        af[mf], bf[nf], acc[mf][nf], 0, 0, 0);
        }
    }
    int hi = lane >> 4;
#pragma unroll
    for (int nf = 0; nf < 4; nf++) {
        int col = n0 + wc + nf * 16 + fr;
        float bias = b1[col];
#pragma unroll
        for (int mf = 0; mf < 4; mf++) {
            int r0 = wr + mf * 16 + hi * 4;
#pragma unroll
            for (int r = 0; r < 4; r++) {
                float v = fmaxf(acc[mf][nf][r] + bias, 0.f);
                h[(size_t)(m0 + r0 + r) * HDIM + col] = f2bf(v);
            }
        }
    }
}

// gemm2y: yb[e][m][n] = wt[e][m] * (h[e][m] @ W2T[e][n] + b2[e][n]);  z = expert
__global__ __launch_bounds__(256) void gemm2y_kernel(
    const unsigned short* __restrict__ h, const unsigned short* __restrict__ w2t,
    const float* __restrict__ b2, const float* __restrict__ wt_list,
    float* __restrict__ yb) {
    int e = blockIdx.z;
    h       += (size_t)e * KCAP * HDIM;
    w2t     += (size_t)e * DDIM * HDIM;
    b2      += (size_t)e * DDIM;
    wt_list += (size_t)e * KCAP;
    yb      += (size_t)e * KCAP * DDIM;
    __shared__ unsigned short As[128 * 64];
    __shared__ unsigned short Bs[128 * 64];
    __shared__ float wts[128];
    int t = threadIdx.x;
    int m0 = blockIdx.x * 128, n0 = blockIdx.y * 128;
    if (t < 128) wts[t] = wt_list[m0 + t];
    int w = t >> 6, lane = t & 63;
    int lrow8 = lane >> 3, lcol = lane & 7;
    unsigned swz = (unsigned)(((lcol ^ lrow8) & 7) << 4);
    const char* aptr[4]; const char* bptr[4];
    unsigned short* alds[4]; unsigned short* blds[4];
#pragma unroll
    for (int i = 0; i < 4; i++) {
        int rr = i * 32 + w * 8 + lrow8;
        aptr[i] = (const char*)(h + (size_t)(m0 + rr) * HDIM) + swz;
        bptr[i] = (const char*)(w2t + (size_t)(n0 + rr) * HDIM) + swz;
        alds[i] = As + (i * 32 + w * 8) * 64;
        blds[i] = Bs + (i * 32 + w * 8) * 64;
    }
    f32x4 acc[4][4] = {};
    int fr = lane & 15, kg = lane >> 4;
    int wr = (w >> 1) * 64, wc = (w & 1) * 64;
    for (int kt = 0; kt < HDIM; kt += 64) {
        __syncthreads();
#pragma unroll
        for (int i = 0; i < 4; i++) {
            gl_lds16(aptr[i], alds[i]);
            gl_lds16(bptr[i], blds[i]);
            aptr[i] += 128; bptr[i] += 128;
        }
        __syncthreads();
#pragma unroll
        for (int kk = 0; kk < 2; kk++) {
            bf16x8 af[4], bf[4];
#pragma unroll
            for (int mf = 0; mf < 4; mf++) {
                int r = wr + mf * 16 + fr;
                int byte = (r * 128 + kk * 64 + kg * 16) ^ ((r & 7) << 4);
                af[mf] = *(const bf16x8*)((const char*)As + byte);
            }
#pragma unroll
            for (int nf = 0; nf < 4; nf++) {
                int r = wc + nf * 16 + fr;
                int byte = (r * 128 + kk * 64 + kg * 16) ^ ((r & 7) << 4);
                bf[nf] = *(const bf16x8*)((const char*)Bs + byte);
            }
#pragma unroll
            for (int mf = 0; mf < 4; mf++)
#pragma unroll
                for (int nf = 0; nf < 4; nf++)
                    acc[mf][nf] = __builtin_amdgcn_mfma_f32_16x16x32_bf16(
                        af[mf], bf[nf], acc[mf][nf], 0, 0, 0);
        }
    }
    int hi = lane >> 4;
#pragma unroll
    for (int nf = 0; nf < 4; nf++) {
        int col = n0 + wc + nf * 16 + fr;
        float bias = b2[col];
#pragma unroll
        for (int mf = 0; mf < 4; mf++) {
            int r0 = wr + mf * 16 + hi * 4;
#pragma unroll
            for (int r = 0; r < 4; r++) {
                int lrow = r0 + r;
                yb[(size_t)(m0 + lrow) * DDIM + col] = wts[lrow] * (acc[mf][nf][r] + bias);
            }
        }
    }
}

// gemm2 fallback (per-expert path): atomic accumulate into out; z = split-K half
__global__ __launch_bounds__(256) void gemm2_fb(
    const unsigned short* __restrict__ h, const unsigned short* __restrict__ w2t,
    const float* __restrict__ b2, const int* __restrict__ idx_list,
    const float* __restrict__ wt_list, float* __restrict__ out) {
    __shared__ unsigned short As[128 * 64];
    __shared__ unsigned short Bs[128 * 64];
    __shared__ int toks[128];
    __shared__ float wts[128];
    int t = threadIdx.x;
    int m0 = blockIdx.x * 128, n0 = blockIdx.y * 128;
    int z = blockIdx.z;
    if (t < 128) { toks[t] = idx_list[m0 + t]; wts[t] = wt_list[m0 + t]; }
    __syncthreads();
    int w = t >> 6, lane = t & 63;
    int lrow8 = lane >> 3, lcol = lane & 7;
    unsigned swz = (unsigned)(((lcol ^ lrow8) & 7) << 4);
    const char* aptr[4]; const char* bptr[4];
    unsigned short* alds[4]; unsigned short* blds[4];
#pragma unroll
    for (int i = 0; i < 4; i++) {
        int rr = i * 32 + w * 8 + lrow8;
        aptr[i] = (const char*)(h + (size_t)(m0 + rr) * HDIM + z * 2048) + swz;
        bptr[i] = (const char*)(w2t + (size_t)(n0 + rr) * HDIM + z * 2048) + swz;
        alds[i] = As + (i * 32 + w * 8) * 64;
        blds[i] = Bs + (i * 32 + w * 8) * 64;
    }
    f32x4 acc[4][4] = {};
    int fr = lane & 15, kg = lane >> 4;
    int wr = (w >> 1) * 64, wc = (w & 1) * 64;
    for (int kt = 0; kt < 2048; kt += 64) {
        __syncthreads();
#pragma unroll
        for (int i = 0; i < 4; i++) {
            gl_lds16(aptr[i], alds[i]);
            gl_lds16(bptr[i], blds[i]);
            aptr[i] += 128; bptr[i] += 128;
        }
        __syncthreads();
#pragma unroll
        for (int kk = 0; kk < 2; kk++) {
            bf16x8 af[4], bf[4];
#pragma unroll
            for (int mf = 0; mf < 4; mf++) {
                int r = wr + mf * 16 + fr;
                int byte = (r * 128 + kk * 64 + kg * 16) ^ ((r & 7) << 4);
                af[mf] = *(const bf16x8*)((const char*)As + byte);
            }
#pragma unroll
            for (int nf = 0; nf < 4; nf++) {
                int r = wc + nf * 16 + fr;
                int byte = (r * 128 + kk * 64 + kg * 16) ^ ((r & 7) << 4);
                bf[nf] = *(const bf16x8*)((const char*)Bs + byte);
            }
#pragma unroll
            for (int mf = 0; mf < 4; mf++)
#pragma unroll
                for (int nf = 0; nf < 4; nf++)
                    acc[mf][nf] = __builtin_amdgcn_mfma_f32_16x16x32_bf16(
                        af[mf], bf[nf], acc[mf][nf], 0, 0, 0);
        }
    }
    int hi = lane >> 4;
#pragma unroll
    for (int nf = 0; nf < 4; nf++) {
        int col = n0 + wc + nf * 16 + fr;
        float bias = (z == 0) ? b2[col] : 0.f;
#pragma unroll
        for (int mf = 0; mf < 4; mf++) {
            int r0 = wr + mf * 16 + hi * 4;
#pragma unroll
            for (int r = 0; r < 4; r++) {
                int lrow = r0 + r;
                atomicAdd(&out[(size_t)toks[lrow] * DDIM + col],
                          wts[lrow] * (acc[mf][nf][r] + bias));
            }
        }
    }
}

// ---------------- combine: out[b] = sum_e yb[e][inv[e][b]] ----------------
__global__ __launch_bounds__(256) void combine_kernel(
    const float* __restrict__ yb, const int* __restrict__ inv,
    float* __restrict__ out) {
    int b = blockIdx.x, t = threadIdx.x;
    float4 acc = {0.f, 0.f, 0.f, 0.f};
#pragma unroll
    for (int e = 0; e < NEXP; e++) {
        int s = inv[(size_t)e * BTOK + b];
        if (s >= 0) {
            float4 v = *(const float4*)(yb + ((size_t)e * KCAP + s) * DDIM + t * 4);
            acc.x += v.x; acc.y += v.y; acc.z += v.z; acc.w += v.w;
        }
    }
    *(float4*)(out + (size_t)b * DDIM + t * 4) = acc;
}

extern "C" void kernel_launch(void* const* d_in, const int* in_sizes, int n_in,
                              void* d_out, int out_size, void* d_ws, size_t ws_size,
                              hipStream_t stream) {
    const float* x  = (const float*)d_in[0];
    const float* Wr = (const float*)d_in[1];
    const float* br = (const float*)d_in[2];
    const float* W1 = (const float*)d_in[3];
    const float* b1 = (const float*)d_in[4];
    const float* W2 = (const float*)d_in[5];
    const float* b2 = (const float*)d_in[6];
    float* out = (float*)d_out;

    char* ws = (char*)d_ws;
    float*    gateT    = (float*)ws;                       // 256 KB
    unsigned* meta     = (unsigned*)(ws + 262144);         // cutoff[8], ngt[8]
    unsigned* cnt      = meta + 16;
    int*      idx_list = (int*)(ws + 327680);              // 64 KB
    float*    wt_list  = (float*)(ws + 393216);            // 64 KB
    int*      inv      = (int*)(ws + 458752);              // 256 KB
    unsigned short* xbuf = (unsigned short*)(ws + 1 * MB); // 16 MB

    // batched plan layout
    unsigned short* w1t  = (unsigned short*)(ws + 17 * MB);   // 64 MB
    unsigned short* w2t  = (unsigned short*)(ws + 81 * MB);   // 64 MB
    unsigned short* hbuf = (unsigned short*)(ws + 145 * MB);  // 128 MB
    float*          yb   = (float*)(ws + 273 * MB);           // 64 MB
    const size_t NEED_BATCH = 337 * MB;
    // per-expert fallback layout
    unsigned short* w1t_pe = (unsigned short*)(ws + 17 * MB); // 8 MB
    unsigned short* w2t_pe = (unsigned short*)(ws + 25 * MB); // 8 MB
    unsigned short* h_pe   = (unsigned short*)(ws + 33 * MB); // 16 MB
    const size_t NEED_PE = 49 * MB;

    bool batched = (ws_size >= NEED_BATCH);
    if (!batched && ws_size < NEED_PE) return;

    hipMemsetAsync(cnt, 0, NEXP * sizeof(unsigned), stream);

    router_kernel<<<dim3(BTOK / 4), 256, 0, stream>>>(x, Wr, br, gateT, xbuf);
    select_kernel<<<dim3(NEXP), 256, 0, stream>>>(gateT, meta);
    build_kernel<<<dim3(BTOK / 256, NEXP), 256, 0, stream>>>(gateT, meta, cnt, idx_list, wt_list);
    tie_kernel<<<dim3(NEXP), 256, 0, stream>>>(gateT, meta, cnt, idx_list, wt_list);

    if (batched) {
        hipMemsetAsync(inv, 0xFF, (size_t)NEXP * BTOK * sizeof(int), stream);
        tcvt_kernel<<<dim3(HDIM / 64, DDIM / 64, NEXP), 256, 0, stream>>>(W1, w1t, DDIM, HDIM);
        tcvt_kernel<<<dim3(DDIM / 64, HDIM / 64, NEXP), 256, 0, stream>>>(W2, w2t, HDIM, DDIM);
        invb_kernel<<<dim3(NEXP * KCAP / 256), 256, 0, stream>>>(idx_list, inv);
        gemm1_kernel<<<dim3(KCAP / 128, HDIM / 128, NEXP), 256, 0, stream>>>(
            xbuf, w1t, b1, idx_list, hbuf);
        gemm2y_kernel<<<dim3(KCAP / 128, DDIM / 128, NEXP), 256, 0, stream>>>(
            hbuf, w2t, b2, wt_list, yb);
        combine_kernel<<<dim3(BTOK), 256, 0, stream>>>(yb, inv, out);
    } else {
        hipMemsetAsync(d_out, 0, (size_t)out_size * sizeof(float), stream);
        for (int e = 0; e < NEXP; e++) {
            tcvt_kernel<<<dim3(HDIM / 64, DDIM / 64, 1), 256, 0, stream>>>(
                W1 + (size_t)e * DDIM * HDIM, w1t_pe, DDIM, HDIM);
            gemm1_kernel<<<dim3(KCAP / 128, HDIM / 128, 1), 256, 0, stream>>>(
                xbuf, w1t_pe, b1 + (size_t)e * HDIM, idx_list + (size_t)e * KCAP, h_pe);
            tcvt_kernel<<<dim3(DDIM / 64, HDIM / 64, 1), 256, 0, stream>>>(
                W2 + (size_t)e * HDIM * DDIM, w2t_pe, HDIM, DDIM);
            gemm2_fb<<<dim3(KCAP / 128, DDIM / 128, 2), 256, 0, stream>>>(
                h_pe, w2t_pe, b2 + (size_t)e * DDIM, idx_list + (size_t)e * KCAP,
                wt_list + (size_t)e * KCAP, out);
        }
    }
}